// Round 8
// baseline (196.197 us; speedup 1.0000x reference)
//
#include <hip/hip_runtime.h>

// Flash attention, non-causal: O = softmax(Q K^T / sqrt(64)) V
// B=64, S=2048, D=64, fp32 in/out, bf16 MFMA compute (fp32 accum).
//
// R17 = R14 (96.7us, verified) + KVBLK=128 ONLY. Completes the R15
// bisect: R16 showed the fat-wave compute NaNs even with verified
// staging (parked -- suspected regalloc/spill interaction, undiagnosable
// without disasm). R17 keeps R14's per-wave compute BYTE-FOR-BYTE
// (32 q/wave, scalar z per t, oacc[2], scalar rs, grid 64x8,
// launch_bounds(512,4)) and only doubles the K/V tile: t-loop 0..3,
// ksh[2][128*72], vsh[2][64*136], kx[4]/vv[16] staging where wave w owns
// exactly 16-key V-block w (permuted sub-offsets {0,8,4,12}). Barriers
// halve (16 total), staging writes/key drop, prefetch distance doubles.
// LDS 71.7 KB -> still 2 blocks/CU.

typedef short bf16x8 __attribute__((ext_vector_type(8)));
typedef float f32x16 __attribute__((ext_vector_type(16)));

#define SQK 0.18033688011112042f /* (1/8) * log2(e) : softmax in exp2 domain */

__device__ __forceinline__ short f2bf(float x) {
  unsigned u = __float_as_uint(x);
  u = (u + 0x7fffu + ((u >> 16) & 1u)) >> 16;  // RNE (one-time Q conv only)
  return (short)u;
}

// pack two floats to bf16x2 in ONE instruction (RNE): lo -> [15:0], hi -> [31:16]
__device__ __forceinline__ unsigned pk2(float lo, float hi) {
  unsigned r;
  asm("v_cvt_pk_bf16_f32 %0, %1, %2" : "=v"(r) : "v"(lo), "v"(hi));
  return r;
}

__global__ __launch_bounds__(512, 4) void DotProductAttention_44573170598739_kernel(
    const float* __restrict__ Q, const float* __restrict__ K,
    const float* __restrict__ V, float* __restrict__ O) {
  constexpr int S = 2048, D = 64;
  const int b   = blockIdx.x;                // batch (XCD-locality swizzle)
  const int q0  = blockIdx.y * 256;          // block's first q row
  const int tid = threadIdx.x;
  const int w    = tid >> 6;                 // wave 0..7, owns 32 q rows
  const int lane = tid & 63;
  const int hi   = lane >> 5;                // half-wave 0/1
  const int r32  = lane & 31;

  // double-buffered tiles, KVBLK = 128 keys
  __shared__ __align__(16) short ksh[2][128 * 72];  // K tile, row-major [key][d]
  __shared__ __align__(16) short vsh[2][64 * 136];  // V tile, [d][col]; cols permuted
                                                    // within each 16-key block:
                                                    // col = (k&3)|((k&4)<<1)|((k&8)>>1)

  // ---- Q fragments (regs, whole kernel), pre-scaled into exp2 domain.
  // B-operand of swapped QK: qf[dd] = Q[q = q0+w*32+r32][d = 16dd + 8hi + j]
  bf16x8 qf[4];
#pragma unroll
  for (int dd = 0; dd < 4; ++dd) {
    const float* qp = Q + ((size_t)b * S + q0 + w * 32 + r32) * D + dd * 16 + hi * 8;
    float4 x = ((const float4*)qp)[0];
    float4 y = ((const float4*)qp)[1];
    bf16x8 f;
    f[0] = f2bf(x.x * SQK); f[1] = f2bf(x.y * SQK);
    f[2] = f2bf(x.z * SQK); f[3] = f2bf(x.w * SQK);
    f[4] = f2bf(y.x * SQK); f[5] = f2bf(y.y * SQK);
    f[6] = f2bf(y.z * SQK); f[7] = f2bf(y.w * SQK);
    qf[dd] = f;
  }

  f32x16 oacc[2] = {};        // O: D[row=q(16 rows)][col = d = 32dt + r32]
  float rs = 0.f;             // this lane's share of rowsum[q = r32]
  const f32x16 z16c = {};     // persistent zero C-operand (never written)

  const float* Kb = K + (size_t)b * S * D;
  const float* Vb = V + (size_t)b * S * D;

  float4 kx[4];
  float  vv[16];

  // V staging: wave w holds V rows (keys) w*16..w*16+15 = exactly 16-key
  // block w. Permuted sub-offsets for j-quads {0-3,4-7,8-11,12-15} are
  // {0,8,4,12}: col = 16w + perm(j), perm(j) = (j&3)|((j&4)<<1)|((j&8)>>1).

  // ---- prologue: tile 0 regs -> buf0; tile 1 loads left in flight
#pragma unroll
  for (int i = 0; i < 4; ++i)
    kx[i] = ((const float4*)Kb)[tid + 512 * i];
#pragma unroll
  for (int j = 0; j < 16; ++j)
    vv[j] = Vb[(w * 16 + j) * D + lane];
#pragma unroll
  for (int i = 0; i < 4; ++i) {
    int f = 4 * tid + 2048 * i;
    int row = f >> 6, col = f & 63;
    uint2 pk = { pk2(kx[i].x, kx[i].y), pk2(kx[i].z, kx[i].w) };
    *(uint2*)&ksh[0][row * 72 + col] = pk;
  }
  {
    const int base = lane * 136 + 16 * w;
    uint2 p0 = { pk2(vv[0],  vv[1]),  pk2(vv[2],  vv[3])  };
    uint2 p1 = { pk2(vv[4],  vv[5]),  pk2(vv[6],  vv[7])  };
    uint2 p2 = { pk2(vv[8],  vv[9]),  pk2(vv[10], vv[11]) };
    uint2 p3 = { pk2(vv[12], vv[13]), pk2(vv[14], vv[15]) };
    *(uint2*)&vsh[0][base + 0]  = p0;
    *(uint2*)&vsh[0][base + 8]  = p1;
    *(uint2*)&vsh[0][base + 4]  = p2;
    *(uint2*)&vsh[0][base + 12] = p3;
  }
#pragma unroll
  for (int i = 0; i < 4; ++i)
    kx[i] = ((const float4*)(Kb + 128 * D))[tid + 512 * i];
#pragma unroll
  for (int j = 0; j < 16; ++j)
    vv[j] = Vb[(128 + w * 16 + j) * D + lane];
  __syncthreads();

  int p = 0;
  for (int kt = 0; kt < S; kt += 128, p ^= 1) {
    // ---- stage tile kt+128 (regs from last iter) into buf p^1, then issue
    // loads for tile kt+256. buf[p^1] reads finished before last barrier.
    if (kt + 128 < S) {
#pragma unroll
      for (int i = 0; i < 4; ++i) {
        int f = 4 * tid + 2048 * i;
        int row = f >> 6, col = f & 63;
        uint2 pk = { pk2(kx[i].x, kx[i].y), pk2(kx[i].z, kx[i].w) };
        *(uint2*)&ksh[p ^ 1][row * 72 + col] = pk;
      }
      {
        const int base = lane * 136 + 16 * w;
        uint2 p0 = { pk2(vv[0],  vv[1]),  pk2(vv[2],  vv[3])  };
        uint2 p1 = { pk2(vv[4],  vv[5]),  pk2(vv[6],  vv[7])  };
        uint2 p2 = { pk2(vv[8],  vv[9]),  pk2(vv[10], vv[11]) };
        uint2 p3 = { pk2(vv[12], vv[13]), pk2(vv[14], vv[15]) };
        *(uint2*)&vsh[p ^ 1][base + 0]  = p0;
        *(uint2*)&vsh[p ^ 1][base + 8]  = p1;
        *(uint2*)&vsh[p ^ 1][base + 4]  = p2;
        *(uint2*)&vsh[p ^ 1][base + 12] = p3;
      }
      if (kt + 256 < S) {
        const float* Kg2 = Kb + (size_t)(kt + 256) * D;
        const float* Vg2 = Vb + (size_t)(kt + 256) * D;
#pragma unroll
        for (int i = 0; i < 4; ++i)
          kx[i] = ((const float4*)Kg2)[tid + 512 * i];
#pragma unroll
        for (int j = 0; j < 16; ++j)
          vv[j] = Vg2[(w * 16 + j) * D + lane];
      }
    }

    const short* kshp = ksh[p];
    const short* vshp = vsh[p];
#pragma unroll
    for (int t = 0; t < 4; ++t) {
      // K fragments (A-operand): kf[dd] = K[key=32t+r32][d=16dd+8hi+j]
      bf16x8 kf[4];
#pragma unroll
      for (int dd = 0; dd < 4; ++dd)
        kf[dd] = *(const bf16x8*)&kshp[(t * 32 + r32) * 72 + dd * 16 + hi * 8];

      // ---- QK^T swapped: z = K_tile(32 keys) x Q^T(32 q), accum over d.
      // D[row = key_in_tile = (reg&3)+8(reg>>2)+4hi][col = q = r32]
      __builtin_amdgcn_s_setprio(1);
      f32x16 z = __builtin_amdgcn_mfma_f32_32x32x16_bf16(kf[0], qf[0], z16c, 0, 0, 0);
      z = __builtin_amdgcn_mfma_f32_32x32x16_bf16(kf[1], qf[1], z, 0, 0, 0);
      z = __builtin_amdgcn_mfma_f32_32x32x16_bf16(kf[2], qf[2], z, 0, 0, 0);
      z = __builtin_amdgcn_mfma_f32_32x32x16_bf16(kf[3], qf[3], z, 0, 0, 0);
      __builtin_amdgcn_s_setprio(0);

      // ---- per 16-key half: exp2, row-sum add, pack, PV mfma.
      // e[i] = P[q=r32][key = base + (i&3)+8(i>>2)+4hi], base = 128kt'+32t+16h.
      // vsh's permuted cols make vf element j the matching V row.
#pragma unroll
      for (int h = 0; h < 2; ++h) {
        float e0 = __builtin_amdgcn_exp2f(z[8 * h + 0]);
        float e1 = __builtin_amdgcn_exp2f(z[8 * h + 1]);
        float e2 = __builtin_amdgcn_exp2f(z[8 * h + 2]);
        float e3 = __builtin_amdgcn_exp2f(z[8 * h + 3]);
        float e4 = __builtin_amdgcn_exp2f(z[8 * h + 4]);
        float e5 = __builtin_amdgcn_exp2f(z[8 * h + 5]);
        float e6 = __builtin_amdgcn_exp2f(z[8 * h + 6]);
        float e7 = __builtin_amdgcn_exp2f(z[8 * h + 7]);
        rs += ((e0 + e1) + (e2 + e3)) + ((e4 + e5) + (e6 + e7));
        union { bf16x8 v; unsigned u[4]; } pu;
        pu.u[0] = pk2(e0, e1); pu.u[1] = pk2(e2, e3);
        pu.u[2] = pk2(e4, e5); pu.u[3] = pk2(e6, e7);

        const int cb = t * 32 + h * 16 + hi * 8;
        bf16x8 vf0 = *(const bf16x8*)&vshp[r32 * 136 + cb];
        bf16x8 vf1 = *(const bf16x8*)&vshp[(32 + r32) * 136 + cb];

        __builtin_amdgcn_s_setprio(1);
        oacc[0] = __builtin_amdgcn_mfma_f32_32x32x16_bf16(pu.v, vf0, oacc[0], 0, 0, 0);
        oacc[1] = __builtin_amdgcn_mfma_f32_32x32x16_bf16(pu.v, vf1, oacc[1], 0, 0, 0);
        __builtin_amdgcn_s_setprio(0);
      }
    }
    __syncthreads();
  }

  // ---- epilogue: full rowsum for q=r32 (combine both hi halves), then
  // gather the rowsum each oacc row needs via one-time shfls.
  float tot = rs + __shfl_xor(rs, 32);
#pragma unroll
  for (int g = 0; g < 16; ++g) {
    int rq = (g & 3) + 8 * (g >> 2) + 4 * hi;   // q-offset within wave's 32
    float inv = 1.0f / __shfl(tot, rq);          // lane rq holds rowsum[q=rq]
    int q = q0 + w * 32 + rq;
    float* op = O + ((size_t)b * S + q) * D + r32;
    op[0]  = oacc[0][g] * inv;
    op[32] = oacc[1][g] * inv;
  }
}

extern "C" void kernel_launch(void* const* d_in, const int* in_sizes, int n_in,
                              void* d_out, int out_size, void* d_ws, size_t ws_size,
                              hipStream_t stream) {
  (void)in_sizes; (void)n_in; (void)out_size; (void)d_ws; (void)ws_size;
  const float* Q = (const float*)d_in[0];
  const float* K = (const float*)d_in[1];
  const float* V = (const float*)d_in[2];
  float* O = (float*)d_out;
  // grid.x = batch so all q-tile blocks of a batch share an XCD (L2 reuse)
  dim3 grid(64, 2048 / 256, 1);
  dim3 block(512, 1, 1);
  hipLaunchKernelGGL(DotProductAttention_44573170598739_kernel,
                     grid, block, 0, stream, Q, K, V, O);
}

// Round 9
// 182.316 us; speedup vs baseline: 1.0761x; 1.0761x over previous
//
#include <hip/hip_runtime.h>

// Flash attention, non-causal: O = softmax(Q K^T / sqrt(64)) V
// B=64, S=2048, D=64, fp32 in/out, bf16 MFMA compute (fp32 accum).
//
// R18 = R14 (96.7us, verified) with 1024-THREAD BLOCKS (16 waves x 32 q
// = q-tile 512), KVBLK=64 and per-wave compute byte-identical to R14.
// R17 post-mortem: KVBLK=128 regressed (104.5us) via scratch spill
// (WRITE_SIZE +9.2MB) from the 4x-unrolled body -- big bodies spill, so
// amortize staging across WAVES instead of across keys. Per-thread
// staging halves (kx[1]+vv[4], 4 pk2, 2 LDS writes vs R14's 10 loads /
// 8 pk2 / 6 writes); body is SMALLER than R14's. Grid 64x4 = 256 blocks
// = 1/CU; id%8 = batch%8 keeps all 4 q-blocks of a batch on one XCD.
// Known risk: 1 block/CU loses cross-block phase interleave at the
// barrier; R17 says barrier count wasn't the limiter, betting staging
// VALU savings win.

typedef short bf16x8 __attribute__((ext_vector_type(8)));
typedef float f32x16 __attribute__((ext_vector_type(16)));

#define SQK 0.18033688011112042f /* (1/8) * log2(e) : softmax in exp2 domain */

__device__ __forceinline__ short f2bf(float x) {
  unsigned u = __float_as_uint(x);
  u = (u + 0x7fffu + ((u >> 16) & 1u)) >> 16;  // RNE (one-time Q conv only)
  return (short)u;
}

// pack two floats to bf16x2 in ONE instruction (RNE): lo -> [15:0], hi -> [31:16]
__device__ __forceinline__ unsigned pk2(float lo, float hi) {
  unsigned r;
  asm("v_cvt_pk_bf16_f32 %0, %1, %2" : "=v"(r) : "v"(lo), "v"(hi));
  return r;
}

__global__ __launch_bounds__(1024, 4) void DotProductAttention_44573170598739_kernel(
    const float* __restrict__ Q, const float* __restrict__ K,
    const float* __restrict__ V, float* __restrict__ O) {
  constexpr int S = 2048, D = 64;
  const int b   = blockIdx.x;                // batch (XCD-locality swizzle)
  const int q0  = blockIdx.y * 512;          // block's first q row
  const int tid = threadIdx.x;
  const int w    = tid >> 6;                 // wave 0..15, owns 32 q rows
  const int lane = tid & 63;
  const int hi   = lane >> 5;                // half-wave 0/1
  const int r32  = lane & 31;

  // double-buffered tiles (R14 layout, verified), KVBLK = 64
  __shared__ __align__(16) short ksh[2][64 * 72];  // K tile, row-major [key][d]
  __shared__ __align__(16) short vsh[2][64 * 72];  // V tile, [d][col], cols permuted:
                                                   // within each 16-key block,
                                                   // col = (k&3) | ((k&4)<<1) | ((k&8)>>1)

  // ---- Q fragments (regs, whole kernel), pre-scaled into exp2 domain.
  // B-operand of swapped QK: qf[dd] = Q[q = q0+w*32+r32][d = 16dd + 8hi + j]
  bf16x8 qf[4];
#pragma unroll
  for (int dd = 0; dd < 4; ++dd) {
    const float* qp = Q + ((size_t)b * S + q0 + w * 32 + r32) * D + dd * 16 + hi * 8;
    float4 x = ((const float4*)qp)[0];
    float4 y = ((const float4*)qp)[1];
    bf16x8 f;
    f[0] = f2bf(x.x * SQK); f[1] = f2bf(x.y * SQK);
    f[2] = f2bf(x.z * SQK); f[3] = f2bf(x.w * SQK);
    f[4] = f2bf(y.x * SQK); f[5] = f2bf(y.y * SQK);
    f[6] = f2bf(y.z * SQK); f[7] = f2bf(y.w * SQK);
    qf[dd] = f;
  }

  f32x16 oacc[2] = {};        // O: D[row=q(16 rows)][col = d = 32dt + r32]
  float rs = 0.f;             // this lane's share of rowsum[q = r32]
  const f32x16 z16c = {};     // persistent zero C-operand (never written)

  const float* Kb = K + (size_t)b * S * D;
  const float* Vb = V + (size_t)b * S * D;

  // V staging: wave w holds keys w*4+j (j<4) = 16-block (w>>2), local key
  // k = 4*(w&3)+j. Permuted col base pb = perm(4*(w&3)) = ((w&1)<<3)|((w&2)<<1)
  // ({0,8,4,12} for w&3 = {0,1,2,3}); within the quad perm is identity.
  const int vcb = 16 * (w >> 2) + (((w & 1) << 3) | ((w & 2) << 1));

  float4 kx;
  float  vv[4];

  // ---- prologue: tile 0 -> buf0; tile 1 loads left in flight
  kx = ((const float4*)Kb)[tid];
#pragma unroll
  for (int j = 0; j < 4; ++j)
    vv[j] = Vb[(w * 4 + j) * D + lane];
  {
    int f = 4 * tid;
    int row = f >> 6, col = f & 63;
    uint2 pk = { pk2(kx.x, kx.y), pk2(kx.z, kx.w) };
    *(uint2*)&ksh[0][row * 72 + col] = pk;
  }
  {
    uint2 pv = { pk2(vv[0], vv[1]), pk2(vv[2], vv[3]) };
    *(uint2*)&vsh[0][lane * 72 + vcb] = pv;
  }
  kx = ((const float4*)(Kb + 64 * D))[tid];
#pragma unroll
  for (int j = 0; j < 4; ++j)
    vv[j] = Vb[(64 + w * 4 + j) * D + lane];
  __syncthreads();

  int p = 0;
  for (int kt = 0; kt < S; kt += 64, p ^= 1) {
    // ---- stage tile kt+64 (regs from last iter) into buf p^1, then issue
    // loads for tile kt+128. buf[p^1] reads finished before last barrier.
    if (kt + 64 < S) {
      {
        int f = 4 * tid;
        int row = f >> 6, col = f & 63;
        uint2 pk = { pk2(kx.x, kx.y), pk2(kx.z, kx.w) };
        *(uint2*)&ksh[p ^ 1][row * 72 + col] = pk;
      }
      {
        uint2 pv = { pk2(vv[0], vv[1]), pk2(vv[2], vv[3]) };
        *(uint2*)&vsh[p ^ 1][lane * 72 + vcb] = pv;
      }
      if (kt + 128 < S) {
        const float* Kg2 = Kb + (size_t)(kt + 128) * D;
        const float* Vg2 = Vb + (size_t)(kt + 128) * D;
        kx = ((const float4*)Kg2)[tid];
#pragma unroll
        for (int j = 0; j < 4; ++j)
          vv[j] = Vg2[(w * 4 + j) * D + lane];
      }
    }

    const short* kshp = ksh[p];
    const short* vshp = vsh[p];
#pragma unroll
    for (int t = 0; t < 2; ++t) {
      // K fragments (A-operand): kf[dd] = K[key=32t+r32][d=16dd+8hi+j]
      bf16x8 kf[4];
#pragma unroll
      for (int dd = 0; dd < 4; ++dd)
        kf[dd] = *(const bf16x8*)&kshp[(t * 32 + r32) * 72 + dd * 16 + hi * 8];

      // ---- QK^T swapped: z = K_tile(32 keys) x Q^T(32 q), accum over d.
      // D[row = key_in_tile = (reg&3)+8(reg>>2)+4hi][col = q = r32]
      __builtin_amdgcn_s_setprio(1);
      f32x16 z = __builtin_amdgcn_mfma_f32_32x32x16_bf16(kf[0], qf[0], z16c, 0, 0, 0);
      z = __builtin_amdgcn_mfma_f32_32x32x16_bf16(kf[1], qf[1], z, 0, 0, 0);
      z = __builtin_amdgcn_mfma_f32_32x32x16_bf16(kf[2], qf[2], z, 0, 0, 0);
      z = __builtin_amdgcn_mfma_f32_32x32x16_bf16(kf[3], qf[3], z, 0, 0, 0);
      __builtin_amdgcn_s_setprio(0);

      // ---- per 16-key half: exp2, row-sum add, pack, PV mfma.
      // e[i] = P[q=r32][key = base + (i&3)+8(i>>2)+4hi], base = 32t+16h.
      // vsh's permuted cols make vf element j the matching V row.
#pragma unroll
      for (int h = 0; h < 2; ++h) {
        float e0 = __builtin_amdgcn_exp2f(z[8 * h + 0]);
        float e1 = __builtin_amdgcn_exp2f(z[8 * h + 1]);
        float e2 = __builtin_amdgcn_exp2f(z[8 * h + 2]);
        float e3 = __builtin_amdgcn_exp2f(z[8 * h + 3]);
        float e4 = __builtin_amdgcn_exp2f(z[8 * h + 4]);
        float e5 = __builtin_amdgcn_exp2f(z[8 * h + 5]);
        float e6 = __builtin_amdgcn_exp2f(z[8 * h + 6]);
        float e7 = __builtin_amdgcn_exp2f(z[8 * h + 7]);
        rs += ((e0 + e1) + (e2 + e3)) + ((e4 + e5) + (e6 + e7));
        union { bf16x8 v; unsigned u[4]; } pu;
        pu.u[0] = pk2(e0, e1); pu.u[1] = pk2(e2, e3);
        pu.u[2] = pk2(e4, e5); pu.u[3] = pk2(e6, e7);

        const int cb = t * 32 + h * 16 + hi * 8;
        bf16x8 vf0 = *(const bf16x8*)&vshp[r32 * 72 + cb];
        bf16x8 vf1 = *(const bf16x8*)&vshp[(32 + r32) * 72 + cb];

        __builtin_amdgcn_s_setprio(1);
        oacc[0] = __builtin_amdgcn_mfma_f32_32x32x16_bf16(pu.v, vf0, oacc[0], 0, 0, 0);
        oacc[1] = __builtin_amdgcn_mfma_f32_32x32x16_bf16(pu.v, vf1, oacc[1], 0, 0, 0);
        __builtin_amdgcn_s_setprio(0);
      }
    }
    __syncthreads();
  }

  // ---- epilogue: full rowsum for q=r32 (combine both hi halves), then
  // gather the rowsum each oacc row needs via one-time shfls.
  float tot = rs + __shfl_xor(rs, 32);
#pragma unroll
  for (int g = 0; g < 16; ++g) {
    int rq = (g & 3) + 8 * (g >> 2) + 4 * hi;   // q-offset within wave's 32
    float inv = 1.0f / __shfl(tot, rq);          // lane rq holds rowsum[q=rq]
    int q = q0 + w * 32 + rq;
    float* op = O + ((size_t)b * S + q) * D + r32;
    op[0]  = oacc[0][g] * inv;
    op[32] = oacc[1][g] * inv;
  }
}

extern "C" void kernel_launch(void* const* d_in, const int* in_sizes, int n_in,
                              void* d_out, int out_size, void* d_ws, size_t ws_size,
                              hipStream_t stream) {
  (void)in_sizes; (void)n_in; (void)out_size; (void)d_ws; (void)ws_size;
  const float* Q = (const float*)d_in[0];
  const float* K = (const float*)d_in[1];
  const float* V = (const float*)d_in[2];
  float* O = (float*)d_out;
  // grid.x = batch: linear block id = x + 64*y -> XCD = id%8 = b%8, so all
  // 4 q-blocks of a batch share one XCD (K/V L2 reuse). 256 blocks = 1/CU.
  dim3 grid(64, 2048 / 512, 1);
  dim3 block(1024, 1, 1);
  hipLaunchKernelGGL(DotProductAttention_44573170598739_kernel,
                     grid, block, 0, stream, Q, K, V, O);
}

// Round 10
// 179.215 us; speedup vs baseline: 1.0948x; 1.0173x over previous
//
#include <hip/hip_runtime.h>

// Flash attention, non-causal: O = softmax(Q K^T / sqrt(64)) V
// B=64, S=2048, D=64, fp32 in/out, bf16 MFMA compute (fp32 accum).
//
// R19 = fat-wave attempt #3, de-risked. R18 (91.7us) counters: LDS 45% +
// VALU 38% + MFMA 30% sum to ~113% of wall -> pipes nearly SERIALIZED;
// the only structural cut of the biggest pipe (LDS) is more q per wave.
// R15/R16 (fat-wave) NaN'd; their one feature never present in a passing
// kernel was TWO live f32x16 QK accumulators (za[2]) at ~196 VGPR. R19
// removes it: KVBLK=32 (minimal body), strictly sequential strips with a
// SINGLE z live, kf[4]+vf cached across both strips (8 LDS reads feed
// 16 MFMA -- half R18's ratio), and ZERO f32x16 arrays (named oa00..oa11,
// qf0/qf1, named vf regs, scalar rs0/rs1). Live ~170 VGPR, lb(512,2).
// All layout algebra byte-identical to verified R13/R14/R18 formulas.
// Spill tripwire: WRITE_SIZE must stay exactly 32768 KB.

typedef short bf16x8 __attribute__((ext_vector_type(8)));
typedef float f32x16 __attribute__((ext_vector_type(16)));

#define SQK 0.18033688011112042f /* (1/8) * log2(e) : softmax in exp2 domain */

__device__ __forceinline__ short f2bf(float x) {
  unsigned u = __float_as_uint(x);
  u = (u + 0x7fffu + ((u >> 16) & 1u)) >> 16;  // RNE (one-time Q conv only)
  return (short)u;
}

// pack two floats to bf16x2 in ONE instruction (RNE): lo -> [15:0], hi -> [31:16]
__device__ __forceinline__ unsigned pk2(float lo, float hi) {
  unsigned r;
  asm("v_cvt_pk_bf16_f32 %0, %1, %2" : "=v"(r) : "v"(lo), "v"(hi));
  return r;
}

// exp2 one 8-score half of z (offset OFF), accumulate rowsum into RS,
// emit packed bf16x8 A-fragment into PUV. Keys of element i:
// base + (i&3) + 8*(i>>2) + 4*hi -- matches vsh's permuted columns.
#define SM_HALF(ZV, OFF, RS, PUV)                                        \
  {                                                                      \
    float e0 = __builtin_amdgcn_exp2f(ZV[OFF + 0]);                      \
    float e1 = __builtin_amdgcn_exp2f(ZV[OFF + 1]);                      \
    float e2 = __builtin_amdgcn_exp2f(ZV[OFF + 2]);                      \
    float e3 = __builtin_amdgcn_exp2f(ZV[OFF + 3]);                      \
    float e4 = __builtin_amdgcn_exp2f(ZV[OFF + 4]);                      \
    float e5 = __builtin_amdgcn_exp2f(ZV[OFF + 5]);                      \
    float e6 = __builtin_amdgcn_exp2f(ZV[OFF + 6]);                      \
    float e7 = __builtin_amdgcn_exp2f(ZV[OFF + 7]);                      \
    RS += ((e0 + e1) + (e2 + e3)) + ((e4 + e5) + (e6 + e7));             \
    union { bf16x8 v; unsigned u[4]; } pu_;                              \
    pu_.u[0] = pk2(e0, e1); pu_.u[1] = pk2(e2, e3);                      \
    pu_.u[2] = pk2(e4, e5); pu_.u[3] = pk2(e6, e7);                      \
    PUV = pu_.v;                                                         \
  }

__global__ __launch_bounds__(512, 2) void DotProductAttention_44573170598739_kernel(
    const float* __restrict__ Q, const float* __restrict__ K,
    const float* __restrict__ V, float* __restrict__ O) {
  constexpr int S = 2048, D = 64;
  const int b   = blockIdx.x;                // batch (XCD-locality swizzle)
  const int q0  = blockIdx.y * 512;          // block's first q row
  const int tid = threadIdx.x;
  const int w    = tid >> 6;                 // wave 0..7, owns 64 q rows
  const int lane = tid & 63;
  const int hi   = lane >> 5;                // half-wave 0/1
  const int r32  = lane & 31;

  // double-buffered tiles, KVBLK = 32 keys
  __shared__ __align__(16) short ksh[2][32 * 72];  // K tile, row-major [key][d]
  __shared__ __align__(16) short vsh[2][64 * 40];  // V tile, [d][key-col], cols
                                                   // permuted within each 16-key
                                                   // block: col = (k&3)|((k&4)<<1)|((k&8)>>1)

  // ---- Q fragments, both strips (regs, whole kernel), exp2-domain scaled.
  // qf{s}[dd] = Q[q = q0 + w*64 + s*32 + r32][d = 16dd + 8hi + j]
  bf16x8 qf0[4], qf1[4];
#pragma unroll
  for (int dd = 0; dd < 4; ++dd) {
    const float* qp = Q + ((size_t)b * S + q0 + w * 64 + r32) * D + dd * 16 + hi * 8;
    float4 x = ((const float4*)qp)[0];
    float4 y = ((const float4*)qp)[1];
    bf16x8 f;
    f[0] = f2bf(x.x * SQK); f[1] = f2bf(x.y * SQK);
    f[2] = f2bf(x.z * SQK); f[3] = f2bf(x.w * SQK);
    f[4] = f2bf(y.x * SQK); f[5] = f2bf(y.y * SQK);
    f[6] = f2bf(y.z * SQK); f[7] = f2bf(y.w * SQK);
    qf0[dd] = f;
  }
#pragma unroll
  for (int dd = 0; dd < 4; ++dd) {
    const float* qp = Q + ((size_t)b * S + q0 + w * 64 + 32 + r32) * D + dd * 16 + hi * 8;
    float4 x = ((const float4*)qp)[0];
    float4 y = ((const float4*)qp)[1];
    bf16x8 f;
    f[0] = f2bf(x.x * SQK); f[1] = f2bf(x.y * SQK);
    f[2] = f2bf(x.z * SQK); f[3] = f2bf(x.w * SQK);
    f[4] = f2bf(y.x * SQK); f[5] = f2bf(y.y * SQK);
    f[6] = f2bf(y.z * SQK); f[7] = f2bf(y.w * SQK);
    qf1[dd] = f;
  }

  // O accumulators, NAMED (no f32x16 arrays anywhere).
  // oa{s}{dhalf}: D[row=q(16 rows)][col = d = 32*dhalf + r32]
  f32x16 oa00 = {}, oa01 = {}, oa10 = {}, oa11 = {};
  float rs0 = 0.f, rs1 = 0.f;  // per-strip lane share of rowsum[q = r32]
  const f32x16 z16c = {};      // persistent zero C-operand (never written)

  const float* Kb = K + (size_t)b * S * D;
  const float* Vb = V + (size_t)b * S * D;

  // V staging: wave w holds keys w*4+j (j<4): 16-block (w>>2), local key
  // 4*(w&3)+j. Permuted col base = ((w&1)<<3)|((w&2)<<1) ({0,8,4,12});
  // within the quad the permutation is identity.
  const int vcb = 16 * (w >> 2) + (((w & 1) << 3) | ((w & 2) << 1));

  float4 kx;
  float  vv[4];

  // ---- prologue: tile 0 -> buf0; tile 1 loads left in flight
  kx = ((const float4*)Kb)[tid];
#pragma unroll
  for (int j = 0; j < 4; ++j)
    vv[j] = Vb[(w * 4 + j) * D + lane];
  {
    int f = 4 * tid;
    int row = f >> 6, col = f & 63;
    uint2 pk = { pk2(kx.x, kx.y), pk2(kx.z, kx.w) };
    *(uint2*)&ksh[0][row * 72 + col] = pk;
  }
  {
    uint2 pv = { pk2(vv[0], vv[1]), pk2(vv[2], vv[3]) };
    *(uint2*)&vsh[0][lane * 40 + vcb] = pv;
  }
  kx = ((const float4*)(Kb + 32 * D))[tid];
#pragma unroll
  for (int j = 0; j < 4; ++j)
    vv[j] = Vb[(32 + w * 4 + j) * D + lane];
  __syncthreads();

  int p = 0;
  for (int kt = 0; kt < S; kt += 32, p ^= 1) {
    // ---- stage tile kt+32 (regs from last iter) into buf p^1, then issue
    // loads for tile kt+64. buf[p^1] reads finished before last barrier.
    if (kt + 32 < S) {
      {
        int f = 4 * tid;
        int row = f >> 6, col = f & 63;
        uint2 pk = { pk2(kx.x, kx.y), pk2(kx.z, kx.w) };
        *(uint2*)&ksh[p ^ 1][row * 72 + col] = pk;
      }
      {
        uint2 pv = { pk2(vv[0], vv[1]), pk2(vv[2], vv[3]) };
        *(uint2*)&vsh[p ^ 1][lane * 40 + vcb] = pv;
      }
      if (kt + 64 < S) {
        const float* Kg2 = Kb + (size_t)(kt + 64) * D;
        const float* Vg2 = Vb + (size_t)(kt + 64) * D;
        kx = ((const float4*)Kg2)[tid];
#pragma unroll
        for (int j = 0; j < 4; ++j)
          vv[j] = Vg2[(w * 4 + j) * D + lane];
      }
    }

    const short* kshp = ksh[p];
    const short* vshp = vsh[p];

    // K fragments (A-operand), shared by BOTH strips:
    // kf[dd] = K[key = r32][d = 16dd + 8hi + j]
    bf16x8 kf[4];
#pragma unroll
    for (int dd = 0; dd < 4; ++dd)
      kf[dd] = *(const bf16x8*)&kshp[r32 * 72 + dd * 16 + hi * 8];

    // V fragments (B-operand), shared by BOTH strips:
    // vf{h}{dhalf} = V[key = 16h + perm(j) + 8hi][d = 32*dhalf + r32]
    bf16x8 vf00 = *(const bf16x8*)&vshp[r32 * 40 + hi * 8];
    bf16x8 vf01 = *(const bf16x8*)&vshp[(32 + r32) * 40 + hi * 8];
    bf16x8 vf10 = *(const bf16x8*)&vshp[r32 * 40 + 16 + hi * 8];
    bf16x8 vf11 = *(const bf16x8*)&vshp[(32 + r32) * 40 + 16 + hi * 8];

    // ================= strip 0 (q = q0 + w*64 + r32) =================
    {
      __builtin_amdgcn_s_setprio(1);
      f32x16 z = __builtin_amdgcn_mfma_f32_32x32x16_bf16(kf[0], qf0[0], z16c, 0, 0, 0);
      z = __builtin_amdgcn_mfma_f32_32x32x16_bf16(kf[1], qf0[1], z, 0, 0, 0);
      z = __builtin_amdgcn_mfma_f32_32x32x16_bf16(kf[2], qf0[2], z, 0, 0, 0);
      z = __builtin_amdgcn_mfma_f32_32x32x16_bf16(kf[3], qf0[3], z, 0, 0, 0);
      __builtin_amdgcn_s_setprio(0);

      bf16x8 pa;
      SM_HALF(z, 0, rs0, pa);
      __builtin_amdgcn_s_setprio(1);
      oa00 = __builtin_amdgcn_mfma_f32_32x32x16_bf16(pa, vf00, oa00, 0, 0, 0);
      oa01 = __builtin_amdgcn_mfma_f32_32x32x16_bf16(pa, vf01, oa01, 0, 0, 0);
      __builtin_amdgcn_s_setprio(0);
      SM_HALF(z, 8, rs0, pa);
      __builtin_amdgcn_s_setprio(1);
      oa00 = __builtin_amdgcn_mfma_f32_32x32x16_bf16(pa, vf10, oa00, 0, 0, 0);
      oa01 = __builtin_amdgcn_mfma_f32_32x32x16_bf16(pa, vf11, oa01, 0, 0, 0);
      __builtin_amdgcn_s_setprio(0);
    }

    // ================= strip 1 (q = q0 + w*64 + 32 + r32) =============
    {
      __builtin_amdgcn_s_setprio(1);
      f32x16 z = __builtin_amdgcn_mfma_f32_32x32x16_bf16(kf[0], qf1[0], z16c, 0, 0, 0);
      z = __builtin_amdgcn_mfma_f32_32x32x16_bf16(kf[1], qf1[1], z, 0, 0, 0);
      z = __builtin_amdgcn_mfma_f32_32x32x16_bf16(kf[2], qf1[2], z, 0, 0, 0);
      z = __builtin_amdgcn_mfma_f32_32x32x16_bf16(kf[3], qf1[3], z, 0, 0, 0);
      __builtin_amdgcn_s_setprio(0);

      bf16x8 pa;
      SM_HALF(z, 0, rs1, pa);
      __builtin_amdgcn_s_setprio(1);
      oa10 = __builtin_amdgcn_mfma_f32_32x32x16_bf16(pa, vf00, oa10, 0, 0, 0);
      oa11 = __builtin_amdgcn_mfma_f32_32x32x16_bf16(pa, vf01, oa11, 0, 0, 0);
      __builtin_amdgcn_s_setprio(0);
      SM_HALF(z, 8, rs1, pa);
      __builtin_amdgcn_s_setprio(1);
      oa10 = __builtin_amdgcn_mfma_f32_32x32x16_bf16(pa, vf10, oa10, 0, 0, 0);
      oa11 = __builtin_amdgcn_mfma_f32_32x32x16_bf16(pa, vf11, oa11, 0, 0, 0);
      __builtin_amdgcn_s_setprio(0);
    }
    __syncthreads();
  }

  // ---- epilogue, per strip: rowsum for q=r32 (combine hi halves), then
  // gather via one-time shfls. Row g of oa** is q-offset (g&3)+8(g>>2)+4hi.
  {
    float tot = rs0 + __shfl_xor(rs0, 32);
#pragma unroll
    for (int g = 0; g < 16; ++g) {
      int rq = (g & 3) + 8 * (g >> 2) + 4 * hi;
      float inv = 1.0f / __shfl(tot, rq);
      int q = q0 + w * 64 + rq;
      float* op = O + ((size_t)b * S + q) * D + r32;
      op[0]  = oa00[g] * inv;
      op[32] = oa01[g] * inv;
    }
  }
  {
    float tot = rs1 + __shfl_xor(rs1, 32);
#pragma unroll
    for (int g = 0; g < 16; ++g) {
      int rq = (g & 3) + 8 * (g >> 2) + 4 * hi;
      float inv = 1.0f / __shfl(tot, rq);
      int q = q0 + w * 64 + 32 + rq;
      float* op = O + ((size_t)b * S + q) * D + r32;
      op[0]  = oa10[g] * inv;
      op[32] = oa11[g] * inv;
    }
  }
}

extern "C" void kernel_launch(void* const* d_in, const int* in_sizes, int n_in,
                              void* d_out, int out_size, void* d_ws, size_t ws_size,
                              hipStream_t stream) {
  (void)in_sizes; (void)n_in; (void)out_size; (void)d_ws; (void)ws_size;
  const float* Q = (const float*)d_in[0];
  const float* K = (const float*)d_in[1];
  const float* V = (const float*)d_in[2];
  float* O = (float*)d_out;
  // grid.x = batch: linear block id = x + 64*y -> XCD = id%8 = b%8, so all
  // 4 q-blocks of a batch share one XCD (K/V L2 reuse). 256 blocks = 1/CU.
  dim3 grid(64, 2048 / 512, 1);
  dim3 block(512, 1, 1);
  hipLaunchKernelGGL(DotProductAttention_44573170598739_kernel,
                     grid, block, 0, stream, Q, K, V, O);
}